// Round 9
// baseline (559.605 us; speedup 1.0000x reference)
//
#include <hip/hip_runtime.h>

typedef _Float16 f16;
typedef _Float16 f16x8 __attribute__((ext_vector_type(8)));
typedef float f32x4 __attribute__((ext_vector_type(4)));
typedef unsigned long long u64;
typedef unsigned u32;

// dims
#define BB 128
#define TT 128
#define IIN 512
#define HHID 512
#define EEX 256

#define AL __ATOMIC_RELAXED
#define SCA __HIP_MEMORY_SCOPE_AGENT

// ---------------- prep: fp32 -> fp16 conversions + counter zeroing ----------------
__global__ void prep_kernel(const float* __restrict__ x,
    const float* __restrict__ W_ir, const float* __restrict__ W_iz, const float* __restrict__ W_in,
    const float* __restrict__ W_hr, const float* __restrict__ W_hz, const float* __restrict__ W_hn,
    f16* __restrict__ xb, f16* __restrict__ WiCat, f16* __restrict__ WhCat,
    u32* __restrict__ cnt)
{
  size_t idx = (size_t)blockIdx.x * 256 + threadIdx.x;

  const size_t NX = (size_t)TT * BB * (IIN / 8);         // 1,048,576 chunks of 8
  const size_t NW = (size_t)2 * 1536 * (512 / 8);        // 196,608 per weight set
  if (idx < NX) {
    int t = (int)(idx / (BB * 64));
    int rem = (int)(idx % (BB * 64));
    int b = rem >> 6;
    int k0 = (rem & 63) * 8;
    const float* src = x + ((size_t)b * TT + t) * IIN + k0;
    f16x8 v;
#pragma unroll
    for (int j = 0; j < 8; ++j) v[j] = (f16)src[j];
    *(f16x8*)(xb + ((size_t)t * BB + b) * IIN + k0) = v;
  } else if (idx < NX + 2 * NW) {
    size_t w = idx - NX;
    bool isI = w < NW;
    size_t w2 = isI ? w : w - NW;
    int l = (int)(w2 / (1536 * 64));
    int rem = (int)(w2 % (1536 * 64));
    int n = rem >> 6;
    int k0 = (rem & 63) * 8;
    int g = n >> 9, j = n & 511;
    const float* W = isI ? (g == 0 ? W_ir : (g == 1 ? W_iz : W_in))
                         : (g == 0 ? W_hr : (g == 1 ? W_hz : W_hn));
    const float* src = W + ((size_t)l * 512 + j) * 512 + k0;
    f16x8 v;
#pragma unroll
    for (int jj = 0; jj < 8; ++jj) v[jj] = (f16)src[jj];
    f16* dst = isI ? WiCat : WhCat;
    *(f16x8*)(dst + ((size_t)l * 1536 + n) * 512 + k0) = v;
  } else if (idx < NX + 2 * NW + 65536) {
    // zero step counters: [2 layers][8 clusters][128 t][32 u32 (128B line)]
    size_t z = idx - (NX + 2 * NW);
    __hip_atomic_store(cnt + z, 0u, AL, SCA);
  }
}

// ---------------- er[l][b][h] = sum_e extra[b][e] * W_er[l][h][e] (f32) ----------------
__global__ void er_kernel(const float* __restrict__ extra, const float* __restrict__ W_er,
                          float* __restrict__ er)
{
  int idx = blockIdx.x * 256 + threadIdx.x;   // 2*128*512 = 131072
  int l = idx >> 16;
  int b = (idx >> 9) & 127;
  int h = idx & 511;
  const float* e = extra + (size_t)b * EEX;
  const float* w = W_er + ((size_t)l * 512 + h) * EEX;
  float acc = 0.f;
#pragma unroll 4
  for (int k = 0; k < EEX; k += 4)
    acc += e[k] * w[k] + e[k + 1] * w[k + 1] + e[k + 2] * w[k + 2] + e[k + 3] * w[k + 3];
  er[idx] = acc;
}

// ---------------- fused 2-layer recurrence: 8-member clusters ----------------
// 128 blocks x 512 threads (8 waves). bid: layer = bid>>6, cluster c = (bid>>3)&7
// (16 batch rows), slice s = bid&7 (64 hid cols). R4-proven agent-scope protocol:
//   data store (relaxed agent) -> per-wave vmcnt(0) -> syncthreads ->
//   tid0 fire-and-forget atomicAdd on the (layer,c,t) counter (own 128B line) ->
//   tid0 polls own counter ==8; layer-1: tid64 polls L0's t+1 counter in PARALLEL ->
//   syncthreads -> pipelined data loads.
// vs R4: arrivals/cluster 16 -> 8 (halves the RMW chain + convoy width),
// pollers 256 -> 128 blocks, counters line-padded, outs/hfin after the arrival.
// Waves 0-3: h @ Wh^T (3 tiles of 16 gate-cols each); waves 4-7: inp @ Wi^T.
__global__ __launch_bounds__(512, 1) void fused_recur(
    const f16* __restrict__ WiCat,   // [2][1536][512]
    const f16* __restrict__ WhCat,   // [2][1536][512]
    const f16* __restrict__ xb,      // [T*128][512]
    const float* __restrict__ er,    // [2][128][512]
    const float* __restrict__ b_ir, const float* __restrict__ b_iz, const float* __restrict__ b_in,
    float* __restrict__ outs,        // [128][T][512]
    float* __restrict__ hfin,        // [2][128][512]
    u32* __restrict__ hx0,           // [T][128][256] u32
    u32* __restrict__ hx1,           // [T][128][256] u32
    u32* __restrict__ cnt)           // [2][8][128][32] u32
{
  const int tid = threadIdx.x;
  const int wave = tid >> 6, lane = tid & 63;
  const int bid = blockIdx.x;
  const int layer = bid >> 6;
  const int c = (bid >> 3) & 7;
  const int s = bid & 7;            // 64-col slice
  const int r16 = lane & 15, khi = lane >> 4;

  __shared__ f16 hL[16 * 520];        // h state, padded rows (520 f16)
  __shared__ f16 xL[16 * 520];        // input rows
  __shared__ float preH[12][16][17];  // h @ Wh^T partials (192 gate cols)
  __shared__ float preX[12][16][17];  // inp @ Wi^T partials

  // ---- pinned weight fragments: waves 0-3 -> Wh ; waves 4-7 -> Wi (3 tiles each) ----
  const bool isWi = wave >= 4;
  const int tb = (wave & 3) * 3;      // tile base 0,3,6,9 (12 tiles of 16 gate-cols)
  const f16* Wsrc = (isWi ? WiCat : WhCat) + (size_t)layer * 1536 * 512;
  f16x8 wf[3][16];
#pragma unroll
  for (int ti = 0; ti < 3; ++ti) {
    int gcl = (tb + ti) * 16 + r16;   // local gate col 0..191
    int g = gcl >> 6, cig = gcl & 63;
    const f16* wr = Wsrc + (size_t)(g * 512 + s * 64 + cig) * 512 + khi * 8;
#pragma unroll
    for (int cc = 0; cc < 16; ++cc) wf[ti][cc] = *(const f16x8*)(wr + cc * 32);
  }
#pragma unroll
  for (int ti = 0; ti < 3; ++ti)
#pragma unroll
    for (int cc = 0; cc < 16; ++cc)
      asm volatile("" : "+v"(wf[ti][cc]));

  // ---- zero h state ----
  {
    f16x8 z;
#pragma unroll
    for (int j = 0; j < 8; ++j) z[j] = (f16)0.f;
    for (int i = tid; i < 16 * 520 / 8; i += 512) ((f16x8*)hL)[i] = z;
  }

  // ---- blend mapping: thread owns (row, cols j0..j0+1) of the 16x64 slice ----
  const int row = tid >> 5, p = tid & 31;
  const int gr = c * 16 + row;
  const int j0 = 2 * p;
  float cbr[2], cbz[2], cbn[2];
#pragma unroll
  for (int e = 0; e < 2; ++e) {
    int jg = s * 64 + j0 + e;
    cbr[e] = b_ir[layer * 512 + jg] + er[((size_t)layer * 128 + gr) * 512 + jg];
    cbz[e] = b_iz[layer * 512 + jg];
    cbn[e] = b_in[layer * 512 + jg];
  }
  float hreg0 = 0.f, hreg1 = 0.f;   // fp32 master h (register-resident)

  u32* hxOwn = layer ? hx1 : hx0;
  u32* cntOwn = cnt + ((size_t)layer * 8 + c) * 128 * 32;
  u32* cntL0 = cnt + (size_t)c * 128 * 32;

  // ---- initial input (t=0) -> xL ----
  if (layer == 0) {
    const u64* sx = (const u64*)xb + ((size_t)0 * 128 + c * 16) * 128;
    u64 xr0[4];
#pragma unroll
    for (int u = 0; u < 4; ++u) xr0[u] = sx[tid + 512 * u];
#pragma unroll
    for (int u = 0; u < 4; ++u) {
      int i = tid + 512 * u, r = i >> 7, q = i & 127;
      *(u64*)(xL + r * 520 + q * 4) = xr0[u];
    }
  } else {
    if (tid == 0)
      while (__hip_atomic_load(cntL0 + 0 * 32, AL, SCA) < 8u)
        __builtin_amdgcn_s_sleep(1);
    __syncthreads();
    const u64* sx = (const u64*)hx0 + ((size_t)0 * 128 + c * 16) * 128;
    u64 xv0[4];
#pragma unroll
    for (int u = 0; u < 4; ++u)
      xv0[u] = __hip_atomic_load(sx + tid + 512 * u, AL, SCA);
#pragma unroll
    for (int u = 0; u < 4; ++u) {
      int i = tid + 512 * u, r = i >> 7, q = i & 127;
      *(u64*)(xL + r * 520 + q * 4) = xv0[u];
    }
  }
  __syncthreads();

  for (int t = 0; t < TT; ++t) {
    // ---- A: MFMA ----
    const f16* aL = isWi ? xL : hL;
    f32x4 ac0 = {0.f, 0.f, 0.f, 0.f}, ac1 = ac0, ac2 = ac0;
#pragma unroll
    for (int cc = 0; cc < 16; ++cc) {
      f16x8 a = *(const f16x8*)(aL + r16 * 520 + cc * 32 + khi * 8);
      ac0 = __builtin_amdgcn_mfma_f32_16x16x32_f16(a, wf[0][cc], ac0, 0, 0, 0);
      ac1 = __builtin_amdgcn_mfma_f32_16x16x32_f16(a, wf[1][cc], ac1, 0, 0, 0);
      ac2 = __builtin_amdgcn_mfma_f32_16x16x32_f16(a, wf[2][cc], ac2, 0, 0, 0);
    }
    {
      float (*pd)[16][17] = isWi ? preX : preH;
#pragma unroll
      for (int v = 0; v < 4; ++v) {
        pd[tb + 0][khi * 4 + v][r16] = ac0[v];
        pd[tb + 1][khi * 4 + v][r16] = ac1[v];
        pd[tb + 2][khi * 4 + v][r16] = ac2[v];
      }
    }
    __syncthreads();   // pre ready; hL/xL free

    // ---- D: blend + coherent h store ----
    float hn[2];
#pragma unroll
    for (int e = 0; e < 2; ++e) {
      int j = j0 + e;
      int jz = 64 + j, jn = 128 + j;
      float sr = preX[j >> 4][row][j & 15] + cbr[e] + preH[j >> 4][row][j & 15];
      float sz = preX[jz >> 4][row][jz & 15] + cbz[e] + preH[jz >> 4][row][jz & 15];
      float pxn = preX[jn >> 4][row][jn & 15] + cbn[e];
      float phn = preH[jn >> 4][row][jn & 15];
      float rg = 1.f / (1.f + __expf(-sr));
      float zg = 1.f / (1.f + __expf(-sz));
      float xn = pxn + rg * phn;
      xn = fminf(15.f, fmaxf(-15.f, xn));
      float e2 = __expf(2.f * xn);
      float nn = (e2 - 1.f) / (e2 + 1.f);
      float hold = e ? hreg1 : hreg0;
      float hv = (1.f - zg) * nn + zg * hold;
      if (e) hreg1 = hv; else hreg0 = hv;
      hn[e] = hv;
    }
    const bool publish = (layer == 0) || (t < TT - 1);
    if (publish) {
      union { f16 h2[2]; u32 u; } pk;
      pk.h2[0] = (f16)hn[0]; pk.h2[1] = (f16)hn[1];
      __hip_atomic_store(hxOwn + ((size_t)t * 128 + gr) * 256 + s * 32 + p, pk.u, AL, SCA);
      // ---- arrival: per-wave ack, barrier, one fire-and-forget RMW ----
      asm volatile("s_waitcnt vmcnt(0)" ::: "memory");
      __syncthreads();
      if (tid == 0)
        __hip_atomic_fetch_add(cntOwn + (size_t)t * 32, 1u, AL, SCA);
    }

    // ---- off-critical-path HBM stores (retire under the poll) ----
    if (layer == 1) {
      float* o = outs + ((size_t)gr * TT + t) * 512 + s * 64 + j0;
      o[0] = hn[0]; o[1] = hn[1];
    }
    if (t == TT - 1) {
      float* hf = hfin + ((size_t)layer * 128 + gr) * 512 + s * 64 + j0;
      hf[0] = hn[0]; hf[1] = hn[1];
      break;
    }

    // ---- xb[t+1] prefetch issue (overlaps poll) ----
    u64 xr[4];
    if (layer == 0) {
      const u64* sx = (const u64*)xb + ((size_t)(t + 1) * 128 + c * 16) * 128;
#pragma unroll
      for (int u = 0; u < 4; ++u) xr[u] = sx[tid + 512 * u];
    }

    // ---- parallel narrow polls: tid0 (own t), tid64 (L0 t+1, layer-1 only) ----
    if (tid == 0)
      while (__hip_atomic_load(cntOwn + (size_t)t * 32, AL, SCA) < 8u)
        __builtin_amdgcn_s_sleep(1);
    if (tid == 64 && layer == 1)
      while (__hip_atomic_load(cntL0 + (size_t)(t + 1) * 32, AL, SCA) < 8u)
        __builtin_amdgcn_s_sleep(1);
    __syncthreads();

    // ---- data loads (pipelined) ----
    u64 hv4[4];
    {
      const u64* hs = (const u64*)hxOwn + ((size_t)t * 128 + c * 16) * 128;
#pragma unroll
      for (int u = 0; u < 4; ++u)
        hv4[u] = __hip_atomic_load(hs + tid + 512 * u, AL, SCA);
    }
    u64 xv4[4];
    if (layer == 1) {
      const u64* xs = (const u64*)hx0 + ((size_t)(t + 1) * 128 + c * 16) * 128;
#pragma unroll
      for (int u = 0; u < 4; ++u)
        xv4[u] = __hip_atomic_load(xs + tid + 512 * u, AL, SCA);
    }

    // ---- write LDS ----
#pragma unroll
    for (int u = 0; u < 4; ++u) {
      int i = tid + 512 * u, r = i >> 7, q = i & 127;
      *(u64*)(hL + r * 520 + q * 4) = hv4[u];
    }
    if (layer == 0) {
#pragma unroll
      for (int u = 0; u < 4; ++u) {
        int i = tid + 512 * u, r = i >> 7, q = i & 127;
        *(u64*)(xL + r * 520 + q * 4) = xr[u];
      }
    } else {
#pragma unroll
      for (int u = 0; u < 4; ++u) {
        int i = tid + 512 * u, r = i >> 7, q = i & 127;
        *(u64*)(xL + r * 520 + q * 4) = xv4[u];
      }
    }
    __syncthreads();   // hL/xL ready for next MFMA
  }
}

// ---------------- launcher ----------------
extern "C" void kernel_launch(void* const* d_in, const int* in_sizes, int n_in,
                              void* d_out, int out_size, void* d_ws, size_t ws_size,
                              hipStream_t stream) {
  const float* x     = (const float*)d_in[0];
  const float* extra = (const float*)d_in[1];
  const float* W_ir  = (const float*)d_in[2];
  const float* b_ir  = (const float*)d_in[3];
  const float* W_hr  = (const float*)d_in[4];
  const float* W_iz  = (const float*)d_in[5];
  const float* b_iz  = (const float*)d_in[6];
  const float* W_hz  = (const float*)d_in[7];
  const float* W_in  = (const float*)d_in[8];
  const float* b_in  = (const float*)d_in[9];
  const float* W_hn  = (const float*)d_in[10];
  const float* W_er  = (const float*)d_in[11];
  float* out = (float*)d_out;

  char* ws = (char*)d_ws;
  f16* WiCat = (f16*)(ws);                    // 3,145,728 B
  f16* WhCat = (f16*)(ws + 3145728);          // 3,145,728 B
  f16* xb    = (f16*)(ws + 6291456);          // 16,777,216 B
  float* er  = (float*)(ws + 23068672);       // 524,288 B
  u32* hx0   = (u32*)(ws + 23592960);         // 16,777,216 B  [T][128][256] u32
  u32* hx1   = (u32*)(ws + 40370176);         // 16,777,216 B
  u32* cnt   = (u32*)(ws + 57147392);         // 262,144 B     [2][8][128][32] u32

  prep_kernel<<<5888, 256, 0, stream>>>(x, W_ir, W_iz, W_in, W_hr, W_hz, W_hn,
                                        xb, WiCat, WhCat, cnt);
  er_kernel<<<512, 256, 0, stream>>>(extra, W_er, er);

  float* outs = out;                              // [128][128][512]
  float* hfin = out + (size_t)BB * TT * HHID;     // [2][128][512]

  fused_recur<<<128, 512, 0, stream>>>(WiCat, WhCat, xb, er, b_ir, b_iz, b_in,
                                       outs, hfin, hx0, hx1, cnt);
}

// Round 11
// 443.282 us; speedup vs baseline: 1.2624x; 1.2624x over previous
//
#include <hip/hip_runtime.h>

typedef _Float16 f16;
typedef _Float16 f16x8 __attribute__((ext_vector_type(8)));
typedef float f32x4 __attribute__((ext_vector_type(4)));
typedef unsigned long long u64;
typedef unsigned u32;

// dims
#define BB 128
#define TT 128
#define IIN 512
#define HHID 512
#define EEX 256

#define AL __ATOMIC_RELAXED
#define SCA __HIP_MEMORY_SCOPE_AGENT

// ---------------- prep: fp32 -> fp16 conversions + counter zeroing ----------------
__global__ void prep_kernel(const float* __restrict__ x,
    const float* __restrict__ W_ir, const float* __restrict__ W_iz, const float* __restrict__ W_in,
    const float* __restrict__ W_hr, const float* __restrict__ W_hz, const float* __restrict__ W_hn,
    f16* __restrict__ xb, f16* __restrict__ WiCat, f16* __restrict__ WhCat,
    u32* __restrict__ cnt)
{
  size_t idx = (size_t)blockIdx.x * 256 + threadIdx.x;

  const size_t NX = (size_t)TT * BB * (IIN / 8);         // 1,048,576 chunks of 8
  const size_t NW = (size_t)2 * 1536 * (512 / 8);        // 196,608 per weight set
  if (idx < NX) {
    int t = (int)(idx / (BB * 64));
    int rem = (int)(idx % (BB * 64));
    int b = rem >> 6;
    int k0 = (rem & 63) * 8;
    const float* src = x + ((size_t)b * TT + t) * IIN + k0;
    f16x8 v;
#pragma unroll
    for (int j = 0; j < 8; ++j) v[j] = (f16)src[j];
    *(f16x8*)(xb + ((size_t)t * BB + b) * IIN + k0) = v;
  } else if (idx < NX + 2 * NW) {
    size_t w = idx - NX;
    bool isI = w < NW;
    size_t w2 = isI ? w : w - NW;
    int l = (int)(w2 / (1536 * 64));
    int rem = (int)(w2 % (1536 * 64));
    int n = rem >> 6;
    int k0 = (rem & 63) * 8;
    int g = n >> 9, j = n & 511;
    const float* W = isI ? (g == 0 ? W_ir : (g == 1 ? W_iz : W_in))
                         : (g == 0 ? W_hr : (g == 1 ? W_hz : W_hn));
    const float* src = W + ((size_t)l * 512 + j) * 512 + k0;
    f16x8 v;
#pragma unroll
    for (int jj = 0; jj < 8; ++jj) v[jj] = (f16)src[jj];
    f16* dst = isI ? WiCat : WhCat;
    *(f16x8*)(dst + ((size_t)l * 1536 + n) * 512 + k0) = v;
  } else if (idx < NX + 2 * NW + 32768) {
    // zero all step counters (2 layers * 8 clusters * 128 t * 16-u32 stride)
    size_t z = idx - (NX + 2 * NW);
    __hip_atomic_store(cnt + z, 0u, AL, SCA);
  }
}

// ---------------- er[l][b][h] = sum_e extra[b][e] * W_er[l][h][e] (f32) ----------------
__global__ void er_kernel(const float* __restrict__ extra, const float* __restrict__ W_er,
                          float* __restrict__ er)
{
  int idx = blockIdx.x * 256 + threadIdx.x;   // 2*128*512 = 131072
  int l = idx >> 16;
  int b = (idx >> 9) & 127;
  int h = idx & 511;
  const float* e = extra + (size_t)b * EEX;
  const float* w = W_er + ((size_t)l * 512 + h) * EEX;
  float acc = 0.f;
#pragma unroll 4
  for (int k = 0; k < EEX; k += 4)
    acc += e[k] * w[k] + e[k + 1] * w[k + 1] + e[k + 2] * w[k + 2] + e[k + 3] * w[k + 3];
  er[idx] = acc;
}

// ---------------- fused 2-layer recurrence (R4 protocol, cleaned placement) ----------------
// 256 blocks x 256 threads (4 waves, 1 wave/SIMD). layer = bid>>7, cluster c = (bid>>4)&7
// (16 batch rows), slice s = bid&15 (32 hid cols).
// R4-proven exchange (best of 7 measured protocol variants, 460us):
//   relaxed-agent data stores -> per-wave vmcnt(0) -> __syncthreads ->
//   tid0 fire-and-forget atomicAdd on cnt[layer][c][t] -> tid0 polls ==16 (s_sleep) ->
//   __syncthreads -> pipelined coherent data loads -> LDS.
// Placement fixes vs R4 (the only changes):
//   1. xb[t+1] prefetch at TOP of step, unpinned -> retires under MFMA+blend; R4's
//      pinned post-arrival prefetch forced a ~700cy vmcnt drain right before the poll.
//   2. outs/hfin HBM stores AFTER the arrival -> out of the vmcnt(0) ack window;
//      they retire under the poll.
__global__ __launch_bounds__(256, 1) void fused_recur(
    const f16* __restrict__ WiCat,   // [2][1536][512]
    const f16* __restrict__ WhCat,   // [2][1536][512]
    const f16* __restrict__ xb,      // [T*128][512]
    const float* __restrict__ er,    // [2][128][512]
    const float* __restrict__ b_ir, const float* __restrict__ b_iz, const float* __restrict__ b_in,
    float* __restrict__ outs,        // [128][T][512]
    float* __restrict__ hfin,        // [2][128][512]
    u32* __restrict__ hx0,           // [T][128][256] u32 (2 f16 each)
    u32* __restrict__ hx1,           // [T][128][256]
    u32* __restrict__ cnt)           // [2][8][128][16] u32
{
  const int tid = threadIdx.x;
  const int wave = tid >> 6, lane = tid & 63;
  const int bid = blockIdx.x;
  const int layer = bid >> 7;
  const int c = (bid >> 4) & 7;
  const int s = bid & 15;
  const int r16 = lane & 15, khi = lane >> 4;

  __shared__ f16 hL[16 * 520];        // h state, padded rows
  __shared__ f16 xL[16 * 520];        // input rows
  __shared__ float preH[6][16][17];   // h @ Wh^T partials (96 gate cols)
  __shared__ float preX[6][16][17];   // inp @ Wi^T partials

  // ---- pinned weight fragments: waves 0,1 -> Wh ; waves 2,3 -> Wi ----
  const bool isWi = wave >= 2;
  const int tb = (wave & 1) * 3;      // tile base within weight-set (3 tiles/wave)
  const f16* Wsrc = (isWi ? WiCat : WhCat) + (size_t)layer * 1536 * 512;
  f16x8 wf[3][16];
#pragma unroll
  for (int ti = 0; ti < 3; ++ti) {
    int gcl = (tb + ti) * 16 + r16;   // local gate col 0..95
    int g = gcl >> 5, cig = gcl & 31;
    const f16* wr = Wsrc + (size_t)(g * 512 + s * 32 + cig) * 512 + khi * 8;
#pragma unroll
    for (int cc = 0; cc < 16; ++cc) wf[ti][cc] = *(const f16x8*)(wr + cc * 32);
  }
#pragma unroll
  for (int ti = 0; ti < 3; ++ti)
#pragma unroll
    for (int cc = 0; cc < 16; ++cc)
      asm volatile("" : "+v"(wf[ti][cc]));

  // ---- zero h state ----
  {
    f16x8 z;
#pragma unroll
    for (int j = 0; j < 8; ++j) z[j] = (f16)0.f;
    for (int i = tid; i < 16 * 520 / 8; i += 256) ((f16x8*)hL)[i] = z;
  }

  // ---- blend mapping: thread owns (row, cols j0..j0+1) of the 16x32 slice ----
  const int row = tid >> 4, p = tid & 15;
  const int gr = c * 16 + row;
  const int j0 = 2 * p;
  float cbr[2], cbz[2], cbn[2];
#pragma unroll
  for (int e = 0; e < 2; ++e) {
    int jg = s * 32 + j0 + e;
    cbr[e] = b_ir[layer * 512 + jg] + er[((size_t)layer * 128 + gr) * 512 + jg];
    cbz[e] = b_iz[layer * 512 + jg];
    cbn[e] = b_in[layer * 512 + jg];
  }
  float hreg0 = 0.f, hreg1 = 0.f;   // fp32 master h (register-resident)

  u32* hxOwn = layer ? hx1 : hx0;
  u32* cntOwn = cnt + ((size_t)layer * 8 + c) * 128 * 16;
  u32* cntL0 = cnt + (size_t)c * 128 * 16;

  // ---- initial input (t=0) -> xL ----
  if (layer == 0) {
    const u64* sx = (const u64*)xb + ((size_t)0 * 128 + c * 16) * 128;
    u64 xr0[8];
#pragma unroll
    for (int u = 0; u < 8; ++u) xr0[u] = sx[tid + 256 * u];
#pragma unroll
    for (int u = 0; u < 8; ++u) {
      int i = tid + 256 * u, r = i >> 7, q = i & 127;
      *(u64*)(xL + r * 520 + q * 4) = xr0[u];
    }
  } else {
    if (tid == 0)
      while (__hip_atomic_load(cntL0 + 0, AL, SCA) < 16u)
        __builtin_amdgcn_s_sleep(1);
    __syncthreads();
    const u64* sx = (const u64*)hx0 + ((size_t)0 * 128 + c * 16) * 128;
    u64 xv0[8];
#pragma unroll
    for (int u = 0; u < 8; ++u)
      xv0[u] = __hip_atomic_load(sx + tid + 256 * u, AL, SCA);
#pragma unroll
    for (int u = 0; u < 8; ++u) {
      int i = tid + 256 * u, r = i >> 7, q = i & 127;
      *(u64*)(xL + r * 520 + q * 4) = xv0[u];
    }
  }
  __syncthreads();

  for (int t = 0; t < TT; ++t) {
    // ---- top-of-step prefetch: xb[t+1] (unpinned; retires under MFMA+blend) ----
    u64 xr[8];
    if (layer == 0 && t < TT - 1) {
      const u64* sx = (const u64*)xb + ((size_t)(t + 1) * 128 + c * 16) * 128;
#pragma unroll
      for (int u = 0; u < 8; ++u) xr[u] = sx[tid + 256 * u];
    }

    // ---- A: MFMA ----
    const f16* aL = isWi ? xL : hL;
    f32x4 ac0 = {0.f, 0.f, 0.f, 0.f}, ac1 = ac0, ac2 = ac0;
#pragma unroll
    for (int cc = 0; cc < 16; ++cc) {
      f16x8 a = *(const f16x8*)(aL + r16 * 520 + cc * 32 + khi * 8);
      ac0 = __builtin_amdgcn_mfma_f32_16x16x32_f16(a, wf[0][cc], ac0, 0, 0, 0);
      ac1 = __builtin_amdgcn_mfma_f32_16x16x32_f16(a, wf[1][cc], ac1, 0, 0, 0);
      ac2 = __builtin_amdgcn_mfma_f32_16x16x32_f16(a, wf[2][cc], ac2, 0, 0, 0);
    }
    {
      float (*pd)[16][17] = isWi ? preX : preH;
#pragma unroll
      for (int v = 0; v < 4; ++v) {
        pd[tb + 0][khi * 4 + v][r16] = ac0[v];
        pd[tb + 1][khi * 4 + v][r16] = ac1[v];
        pd[tb + 2][khi * 4 + v][r16] = ac2[v];
      }
    }
    __syncthreads();   // pre ready; hL/xL free

    // ---- D: blend + coherent h store ----
    float hn[2];
#pragma unroll
    for (int e = 0; e < 2; ++e) {
      int j = j0 + e;
      int jz = 32 + j, jn = 64 + j;
      float sr = preX[j >> 4][row][j & 15] + cbr[e] + preH[j >> 4][row][j & 15];
      float sz = preX[jz >> 4][row][jz & 15] + cbz[e] + preH[jz >> 4][row][jz & 15];
      float pxn = preX[jn >> 4][row][jn & 15] + cbn[e];
      float phn = preH[jn >> 4][row][jn & 15];
      float rg = 1.f / (1.f + __expf(-sr));
      float zg = 1.f / (1.f + __expf(-sz));
      float xn = pxn + rg * phn;
      xn = fminf(15.f, fmaxf(-15.f, xn));
      float e2 = __expf(2.f * xn);
      float nn = (e2 - 1.f) / (e2 + 1.f);
      float hold = e ? hreg1 : hreg0;
      float hv = (1.f - zg) * nn + zg * hold;
      if (e) hreg1 = hv; else hreg0 = hv;
      hn[e] = hv;
    }
    const bool publish = (layer == 0) || (t < TT - 1);
    if (publish) {
      union { f16 h2[2]; u32 u; } pk;
      pk.h2[0] = (f16)hn[0]; pk.h2[1] = (f16)hn[1];
      __hip_atomic_store(hxOwn + ((size_t)t * 128 + gr) * 256 + s * 16 + p, pk.u, AL, SCA);
      // ---- arrival: per-wave ack, barrier, one fire-and-forget RMW ----
      asm volatile("s_waitcnt vmcnt(0)" ::: "memory");
      __syncthreads();
      if (tid == 0)
        __hip_atomic_fetch_add(cntOwn + (size_t)t * 16, 1u, AL, SCA);
    }

    // ---- off-critical-path HBM stores (retire under the poll) ----
    if (layer == 1) {
      float* o = outs + ((size_t)gr * TT + t) * 512 + s * 32 + j0;
      o[0] = hn[0]; o[1] = hn[1];
    }
    if (t == TT - 1) {
      float* hf = hfin + ((size_t)layer * 128 + gr) * 512 + s * 32 + j0;
      hf[0] = hn[0]; hf[1] = hn[1];
      break;
    }

    // ---- poll: tid0, own counter then (layer-1) L0's t+1 counter ----
    if (tid == 0) {
      while (__hip_atomic_load(cntOwn + (size_t)t * 16, AL, SCA) < 16u)
        __builtin_amdgcn_s_sleep(1);
      if (layer == 1)
        while (__hip_atomic_load(cntL0 + (size_t)(t + 1) * 16, AL, SCA) < 16u)
          __builtin_amdgcn_s_sleep(1);
    }
    __syncthreads();

    // ---- data loads (pipelined coherent) ----
    u64 hv8[8];
    {
      const u64* hs = (const u64*)hxOwn + ((size_t)t * 128 + c * 16) * 128;
#pragma unroll
      for (int u = 0; u < 8; ++u)
        hv8[u] = __hip_atomic_load(hs + tid + 256 * u, AL, SCA);
    }
    u64 xv8[8];
    if (layer == 1) {
      const u64* xs = (const u64*)hx0 + ((size_t)(t + 1) * 128 + c * 16) * 128;
#pragma unroll
      for (int u = 0; u < 8; ++u)
        xv8[u] = __hip_atomic_load(xs + tid + 256 * u, AL, SCA);
    }

    // ---- write LDS ----
#pragma unroll
    for (int u = 0; u < 8; ++u) {
      int i = tid + 256 * u, r = i >> 7, q = i & 127;
      *(u64*)(hL + r * 520 + q * 4) = hv8[u];
    }
    if (layer == 0) {
#pragma unroll
      for (int u = 0; u < 8; ++u) {
        int i = tid + 256 * u, r = i >> 7, q = i & 127;
        *(u64*)(xL + r * 520 + q * 4) = xr[u];
      }
    } else {
#pragma unroll
      for (int u = 0; u < 8; ++u) {
        int i = tid + 256 * u, r = i >> 7, q = i & 127;
        *(u64*)(xL + r * 520 + q * 4) = xv8[u];
      }
    }
    __syncthreads();   // hL/xL ready for next MFMA
  }
}

// ---------------- launcher ----------------
extern "C" void kernel_launch(void* const* d_in, const int* in_sizes, int n_in,
                              void* d_out, int out_size, void* d_ws, size_t ws_size,
                              hipStream_t stream) {
  const float* x     = (const float*)d_in[0];
  const float* extra = (const float*)d_in[1];
  const float* W_ir  = (const float*)d_in[2];
  const float* b_ir  = (const float*)d_in[3];
  const float* W_hr  = (const float*)d_in[4];
  const float* W_iz  = (const float*)d_in[5];
  const float* b_iz  = (const float*)d_in[6];
  const float* W_hz  = (const float*)d_in[7];
  const float* W_in  = (const float*)d_in[8];
  const float* b_in  = (const float*)d_in[9];
  const float* W_hn  = (const float*)d_in[10];
  const float* W_er  = (const float*)d_in[11];
  float* out = (float*)d_out;

  char* ws = (char*)d_ws;
  f16* WiCat = (f16*)(ws);                    // 3,145,728 B
  f16* WhCat = (f16*)(ws + 3145728);          // 3,145,728 B
  f16* xb    = (f16*)(ws + 6291456);          // 16,777,216 B
  float* er  = (float*)(ws + 23068672);       // 524,288 B
  u32* hx0   = (u32*)(ws + 23592960);         // 16,777,216 B  [T][128][256] u32
  u32* hx1   = (u32*)(ws + 40370176);         // 16,777,216 B
  u32* cnt   = (u32*)(ws + 57147392);         // 131,072 B     [2][8][128][16] u32

  prep_kernel<<<5760, 256, 0, stream>>>(x, W_ir, W_iz, W_in, W_hr, W_hz, W_hn,
                                        xb, WiCat, WhCat, cnt);
  er_kernel<<<512, 256, 0, stream>>>(extra, W_er, er);

  float* outs = out;                              // [128][128][512]
  float* hfin = out + (size_t)BB * TT * HHID;     // [2][128][512]

  fused_recur<<<256, 256, 0, stream>>>(WiCat, WhCat, xb, er, b_ir, b_iz, b_in,
                                       outs, hfin, hx0, hx1, cnt);
}

// Round 12
// 435.292 us; speedup vs baseline: 1.2856x; 1.0184x over previous
//
#include <hip/hip_runtime.h>

typedef _Float16 f16;
typedef _Float16 f16x8 __attribute__((ext_vector_type(8)));
typedef float f32x4 __attribute__((ext_vector_type(4)));
typedef unsigned long long u64;
typedef unsigned u32;

// dims
#define BB 128
#define TT 128
#define IIN 512
#define HHID 512
#define EEX 256

#define AL __ATOMIC_RELAXED
#define SCA __HIP_MEMORY_SCOPE_AGENT

// ---------------- prep: fp32 -> fp16 conversions + counter zeroing ----------------
__global__ void prep_kernel(const float* __restrict__ x,
    const float* __restrict__ W_ir, const float* __restrict__ W_iz, const float* __restrict__ W_in,
    const float* __restrict__ W_hr, const float* __restrict__ W_hz, const float* __restrict__ W_hn,
    f16* __restrict__ xb, f16* __restrict__ WiCat, f16* __restrict__ WhCat,
    u32* __restrict__ cnt)
{
  size_t idx = (size_t)blockIdx.x * 256 + threadIdx.x;

  const size_t NX = (size_t)TT * BB * (IIN / 8);         // 1,048,576 chunks of 8
  const size_t NW = (size_t)2 * 1536 * (512 / 8);        // 196,608 per weight set
  if (idx < NX) {
    int t = (int)(idx / (BB * 64));
    int rem = (int)(idx % (BB * 64));
    int b = rem >> 6;
    int k0 = (rem & 63) * 8;
    const float* src = x + ((size_t)b * TT + t) * IIN + k0;
    f16x8 v;
#pragma unroll
    for (int j = 0; j < 8; ++j) v[j] = (f16)src[j];
    *(f16x8*)(xb + ((size_t)t * BB + b) * IIN + k0) = v;
  } else if (idx < NX + 2 * NW) {
    size_t w = idx - NX;
    bool isI = w < NW;
    size_t w2 = isI ? w : w - NW;
    int l = (int)(w2 / (1536 * 64));
    int rem = (int)(w2 % (1536 * 64));
    int n = rem >> 6;
    int k0 = (rem & 63) * 8;
    int g = n >> 9, j = n & 511;
    const float* W = isI ? (g == 0 ? W_ir : (g == 1 ? W_iz : W_in))
                         : (g == 0 ? W_hr : (g == 1 ? W_hz : W_hn));
    const float* src = W + ((size_t)l * 512 + j) * 512 + k0;
    f16x8 v;
#pragma unroll
    for (int jj = 0; jj < 8; ++jj) v[jj] = (f16)src[jj];
    f16* dst = isI ? WiCat : WhCat;
    *(f16x8*)(dst + ((size_t)l * 1536 + n) * 512 + k0) = v;
  } else if (idx < NX + 2 * NW + 32768) {
    // zero all step counters (2 layers * 8 clusters * 128 t * 16-u32 stride)
    size_t z = idx - (NX + 2 * NW);
    __hip_atomic_store(cnt + z, 0u, AL, SCA);
  }
}

// ---------------- er[l][b][h] = sum_e extra[b][e] * W_er[l][h][e] (f32) ----------------
__global__ void er_kernel(const float* __restrict__ extra, const float* __restrict__ W_er,
                          float* __restrict__ er)
{
  int idx = blockIdx.x * 256 + threadIdx.x;   // 2*128*512 = 131072
  int l = idx >> 16;
  int b = (idx >> 9) & 127;
  int h = idx & 511;
  const float* e = extra + (size_t)b * EEX;
  const float* w = W_er + ((size_t)l * 512 + h) * EEX;
  float acc = 0.f;
#pragma unroll 4
  for (int k = 0; k < EEX; k += 4)
    acc += e[k] * w[k] + e[k + 1] * w[k + 1] + e[k + 2] * w[k + 2] + e[k + 3] * w[k + 3];
  er[idx] = acc;
}

// ---------------- fused 2-layer recurrence (R11 protocol + pacing-path cuts) ----------------
// 256 blocks x 256 threads (4 waves, 1 wave/SIMD). layer = bid>>7, cluster c = (bid>>4)&7
// (16 batch rows), slice s = bid&15 (32 hid cols).
// Exchange (best of 8 measured protocol variants):
//   relaxed-agent data stores -> per-wave vmcnt(0) -> __syncthreads ->
//   tid0 fire-and-forget atomicAdd on cnt[layer][c][t] ->
//   wave0: lane0 polls own counter, lane1 polls L0's t+1 counter IN PARALLEL ->
//   __syncthreads -> pipelined coherent data loads -> LDS.
// R12 deltas vs R11 (all on the pacing path):
//   1. layer-1's two polls parallelized across lanes 0/1 (were sequential in tid0).
//   2. layer-0's xL write moved pre-poll (xL free after the pre-barrier).
//   3. v_rcp_f32 for the 3 blend divides (precise fdiv ~20cy each without fast-math).
__global__ __launch_bounds__(256, 1) void fused_recur(
    const f16* __restrict__ WiCat,   // [2][1536][512]
    const f16* __restrict__ WhCat,   // [2][1536][512]
    const f16* __restrict__ xb,      // [T*128][512]
    const float* __restrict__ er,    // [2][128][512]
    const float* __restrict__ b_ir, const float* __restrict__ b_iz, const float* __restrict__ b_in,
    float* __restrict__ outs,        // [128][T][512]
    float* __restrict__ hfin,        // [2][128][512]
    u32* __restrict__ hx0,           // [T][128][256] u32 (2 f16 each)
    u32* __restrict__ hx1,           // [T][128][256]
    u32* __restrict__ cnt)           // [2][8][128][16] u32
{
  const int tid = threadIdx.x;
  const int wave = tid >> 6, lane = tid & 63;
  const int bid = blockIdx.x;
  const int layer = bid >> 7;
  const int c = (bid >> 4) & 7;
  const int s = bid & 15;
  const int r16 = lane & 15, khi = lane >> 4;

  __shared__ f16 hL[16 * 520];        // h state, padded rows
  __shared__ f16 xL[16 * 520];        // input rows
  __shared__ float preH[6][16][17];   // h @ Wh^T partials (96 gate cols)
  __shared__ float preX[6][16][17];   // inp @ Wi^T partials

  // ---- pinned weight fragments: waves 0,1 -> Wh ; waves 2,3 -> Wi ----
  const bool isWi = wave >= 2;
  const int tb = (wave & 1) * 3;      // tile base within weight-set (3 tiles/wave)
  const f16* Wsrc = (isWi ? WiCat : WhCat) + (size_t)layer * 1536 * 512;
  f16x8 wf[3][16];
#pragma unroll
  for (int ti = 0; ti < 3; ++ti) {
    int gcl = (tb + ti) * 16 + r16;   // local gate col 0..95
    int g = gcl >> 5, cig = gcl & 31;
    const f16* wr = Wsrc + (size_t)(g * 512 + s * 32 + cig) * 512 + khi * 8;
#pragma unroll
    for (int cc = 0; cc < 16; ++cc) wf[ti][cc] = *(const f16x8*)(wr + cc * 32);
  }
#pragma unroll
  for (int ti = 0; ti < 3; ++ti)
#pragma unroll
    for (int cc = 0; cc < 16; ++cc)
      asm volatile("" : "+v"(wf[ti][cc]));

  // ---- zero h state ----
  {
    f16x8 z;
#pragma unroll
    for (int j = 0; j < 8; ++j) z[j] = (f16)0.f;
    for (int i = tid; i < 16 * 520 / 8; i += 256) ((f16x8*)hL)[i] = z;
  }

  // ---- blend mapping: thread owns (row, cols j0..j0+1) of the 16x32 slice ----
  const int row = tid >> 4, p = tid & 15;
  const int gr = c * 16 + row;
  const int j0 = 2 * p;
  float cbr[2], cbz[2], cbn[2];
#pragma unroll
  for (int e = 0; e < 2; ++e) {
    int jg = s * 32 + j0 + e;
    cbr[e] = b_ir[layer * 512 + jg] + er[((size_t)layer * 128 + gr) * 512 + jg];
    cbz[e] = b_iz[layer * 512 + jg];
    cbn[e] = b_in[layer * 512 + jg];
  }
  float hreg0 = 0.f, hreg1 = 0.f;   // fp32 master h (register-resident)

  u32* hxOwn = layer ? hx1 : hx0;
  u32* cntOwn = cnt + ((size_t)layer * 8 + c) * 128 * 16;
  u32* cntL0 = cnt + (size_t)c * 128 * 16;

  // ---- initial input (t=0) -> xL ----
  if (layer == 0) {
    const u64* sx = (const u64*)xb + ((size_t)0 * 128 + c * 16) * 128;
    u64 xr0[8];
#pragma unroll
    for (int u = 0; u < 8; ++u) xr0[u] = sx[tid + 256 * u];
#pragma unroll
    for (int u = 0; u < 8; ++u) {
      int i = tid + 256 * u, r = i >> 7, q = i & 127;
      *(u64*)(xL + r * 520 + q * 4) = xr0[u];
    }
  } else {
    if (tid == 0)
      while (__hip_atomic_load(cntL0 + 0, AL, SCA) < 16u)
        __builtin_amdgcn_s_sleep(1);
    __syncthreads();
    const u64* sx = (const u64*)hx0 + ((size_t)0 * 128 + c * 16) * 128;
    u64 xv0[8];
#pragma unroll
    for (int u = 0; u < 8; ++u)
      xv0[u] = __hip_atomic_load(sx + tid + 256 * u, AL, SCA);
#pragma unroll
    for (int u = 0; u < 8; ++u) {
      int i = tid + 256 * u, r = i >> 7, q = i & 127;
      *(u64*)(xL + r * 520 + q * 4) = xv0[u];
    }
  }
  __syncthreads();

  for (int t = 0; t < TT; ++t) {
    // ---- top-of-step prefetch: xb[t+1] (unpinned; retires under MFMA+blend) ----
    u64 xr[8];
    if (layer == 0 && t < TT - 1) {
      const u64* sx = (const u64*)xb + ((size_t)(t + 1) * 128 + c * 16) * 128;
#pragma unroll
      for (int u = 0; u < 8; ++u) xr[u] = sx[tid + 256 * u];
    }

    // ---- A: MFMA ----
    const f16* aL = isWi ? xL : hL;
    f32x4 ac0 = {0.f, 0.f, 0.f, 0.f}, ac1 = ac0, ac2 = ac0;
#pragma unroll
    for (int cc = 0; cc < 16; ++cc) {
      f16x8 a = *(const f16x8*)(aL + r16 * 520 + cc * 32 + khi * 8);
      ac0 = __builtin_amdgcn_mfma_f32_16x16x32_f16(a, wf[0][cc], ac0, 0, 0, 0);
      ac1 = __builtin_amdgcn_mfma_f32_16x16x32_f16(a, wf[1][cc], ac1, 0, 0, 0);
      ac2 = __builtin_amdgcn_mfma_f32_16x16x32_f16(a, wf[2][cc], ac2, 0, 0, 0);
    }
    {
      float (*pd)[16][17] = isWi ? preX : preH;
#pragma unroll
      for (int v = 0; v < 4; ++v) {
        pd[tb + 0][khi * 4 + v][r16] = ac0[v];
        pd[tb + 1][khi * 4 + v][r16] = ac1[v];
        pd[tb + 2][khi * 4 + v][r16] = ac2[v];
      }
    }
    __syncthreads();   // pre ready; hL/xL free

    // ---- D: blend + coherent h store ----
    float hn[2];
#pragma unroll
    for (int e = 0; e < 2; ++e) {
      int j = j0 + e;
      int jz = 32 + j, jn = 64 + j;
      float sr = preX[j >> 4][row][j & 15] + cbr[e] + preH[j >> 4][row][j & 15];
      float sz = preX[jz >> 4][row][jz & 15] + cbz[e] + preH[jz >> 4][row][jz & 15];
      float pxn = preX[jn >> 4][row][jn & 15] + cbn[e];
      float phn = preH[jn >> 4][row][jn & 15];
      float rg = __builtin_amdgcn_rcpf(1.f + __expf(-sr));
      float zg = __builtin_amdgcn_rcpf(1.f + __expf(-sz));
      float xn = pxn + rg * phn;
      xn = fminf(15.f, fmaxf(-15.f, xn));
      float e2 = __expf(2.f * xn);
      float nn = 1.f - 2.f * __builtin_amdgcn_rcpf(e2 + 1.f);
      float hold = e ? hreg1 : hreg0;
      float hv = (1.f - zg) * nn + zg * hold;
      if (e) hreg1 = hv; else hreg0 = hv;
      hn[e] = hv;
    }
    const bool publish = (layer == 0) || (t < TT - 1);
    if (publish) {
      union { f16 h2[2]; u32 u; } pk;
      pk.h2[0] = (f16)hn[0]; pk.h2[1] = (f16)hn[1];
      __hip_atomic_store(hxOwn + ((size_t)t * 128 + gr) * 256 + s * 16 + p, pk.u, AL, SCA);
      // ---- arrival: per-wave ack, barrier, one fire-and-forget RMW ----
      asm volatile("s_waitcnt vmcnt(0)" ::: "memory");
      __syncthreads();
      if (tid == 0)
        __hip_atomic_fetch_add(cntOwn + (size_t)t * 16, 1u, AL, SCA);
    }

    // ---- off-critical-path work (retires under the poll) ----
    if (layer == 1) {
      float* o = outs + ((size_t)gr * TT + t) * 512 + s * 32 + j0;
      o[0] = hn[0]; o[1] = hn[1];
    }
    if (t == TT - 1) {
      float* hf = hfin + ((size_t)layer * 128 + gr) * 512 + s * 32 + j0;
      hf[0] = hn[0]; hf[1] = hn[1];
      break;
    }
    if (layer == 0) {
      // xL[t+1] written now (xL free since pre-barrier; xr already retired by the ack)
#pragma unroll
      for (int u = 0; u < 8; ++u) {
        int i = tid + 256 * u, r = i >> 7, q = i & 127;
        *(u64*)(xL + r * 520 + q * 4) = xr[u];
      }
    }

    // ---- poll: wave0, lane0 -> own counter; lane1 -> L0's t+1 (parallel) ----
    if (wave == 0) {
      const u32* pa = cntOwn + (size_t)t * 16;
      const u32* pb = cntL0 + (size_t)(t + 1) * 16;
      bool da = (lane != 0);
      bool db = !(layer == 1 && lane == 1);
      for (;;) {
        if (!da) da = (__hip_atomic_load(pa, AL, SCA) >= 16u);
        if (!db) db = (__hip_atomic_load(pb, AL, SCA) >= 16u);
        if (__all(da && db)) break;
        __builtin_amdgcn_s_sleep(1);
      }
    }
    __syncthreads();

    // ---- data loads (pipelined coherent) ----
    u64 hv8[8];
    {
      const u64* hs = (const u64*)hxOwn + ((size_t)t * 128 + c * 16) * 128;
#pragma unroll
      for (int u = 0; u < 8; ++u)
        hv8[u] = __hip_atomic_load(hs + tid + 256 * u, AL, SCA);
    }
    u64 xv8[8];
    if (layer == 1) {
      const u64* xs = (const u64*)hx0 + ((size_t)(t + 1) * 128 + c * 16) * 128;
#pragma unroll
      for (int u = 0; u < 8; ++u)
        xv8[u] = __hip_atomic_load(xs + tid + 256 * u, AL, SCA);
    }

    // ---- write LDS ----
#pragma unroll
    for (int u = 0; u < 8; ++u) {
      int i = tid + 256 * u, r = i >> 7, q = i & 127;
      *(u64*)(hL + r * 520 + q * 4) = hv8[u];
    }
    if (layer == 1) {
#pragma unroll
      for (int u = 0; u < 8; ++u) {
        int i = tid + 256 * u, r = i >> 7, q = i & 127;
        *(u64*)(xL + r * 520 + q * 4) = xv8[u];
      }
    }
    __syncthreads();   // hL/xL ready for next MFMA
  }
}

// ---------------- launcher ----------------
extern "C" void kernel_launch(void* const* d_in, const int* in_sizes, int n_in,
                              void* d_out, int out_size, void* d_ws, size_t ws_size,
                              hipStream_t stream) {
  const float* x     = (const float*)d_in[0];
  const float* extra = (const float*)d_in[1];
  const float* W_ir  = (const float*)d_in[2];
  const float* b_ir  = (const float*)d_in[3];
  const float* W_hr  = (const float*)d_in[4];
  const float* W_iz  = (const float*)d_in[5];
  const float* b_iz  = (const float*)d_in[6];
  const float* W_hz  = (const float*)d_in[7];
  const float* W_in  = (const float*)d_in[8];
  const float* b_in  = (const float*)d_in[9];
  const float* W_hn  = (const float*)d_in[10];
  const float* W_er  = (const float*)d_in[11];
  float* out = (float*)d_out;

  char* ws = (char*)d_ws;
  f16* WiCat = (f16*)(ws);                    // 3,145,728 B
  f16* WhCat = (f16*)(ws + 3145728);          // 3,145,728 B
  f16* xb    = (f16*)(ws + 6291456);          // 16,777,216 B
  float* er  = (float*)(ws + 23068672);       // 524,288 B
  u32* hx0   = (u32*)(ws + 23592960);         // 16,777,216 B  [T][128][256] u32
  u32* hx1   = (u32*)(ws + 40370176);         // 16,777,216 B
  u32* cnt   = (u32*)(ws + 57147392);         // 131,072 B     [2][8][128][16] u32

  prep_kernel<<<5760, 256, 0, stream>>>(x, W_ir, W_iz, W_in, W_hr, W_hz, W_hn,
                                        xb, WiCat, WhCat, cnt);
  er_kernel<<<512, 256, 0, stream>>>(extra, W_er, er);

  float* outs = out;                              // [128][128][512]
  float* hfin = out + (size_t)BB * TT * HHID;     // [2][128][512]

  fused_recur<<<256, 256, 0, stream>>>(WiCat, WhCat, xb, er, b_ir, b_iz, b_in,
                                       outs, hfin, hx0, hx1, cnt);
}